// Round 5
// baseline (768.374 us; speedup 1.0000x reference)
//
#include <hip/hip_runtime.h>
#include <math.h>

#define FIN 128
#define W 512          // nodes per coarse group
#define S 8            // sub-blocks per group for partial accumulation
#define MAXG 256       // LDS counter capacity (need G=196)
#define HB 256         // edge hist/scatter blocks
#define HT 1024        // edge hist/scatter threads per block
#define BP 100         // radix table padded stride (>= B=98, mult of 4)

// ---------------------------------------------------------------------------
// helpers
// ---------------------------------------------------------------------------
__device__ __forceinline__ long long edge_at(const void* p, long long i, unsigned mode) {
  return mode ? ((const long long*)p)[i] : (long long)((const int*)p)[i];
}

__device__ __forceinline__ void atomic_fadd(float* p, float v) {
  __hip_atomic_fetch_add(p, v, __ATOMIC_RELAXED, __HIP_MEMORY_SCOPE_AGENT);
}

// ---------------------------------------------------------------------------
// dtype detection + zero small scratch
// ---------------------------------------------------------------------------
__global__ void k_detect(const unsigned* ei, unsigned* mode, float* acc,
                         unsigned* btot, int G) {
  int t = threadIdx.x;
  if (t == 0) {
    unsigned orv = 0;
    for (int i = 1; i < 1024; i += 2) orv |= ei[i];
    *mode = (orv == 0) ? 1u : 0u;
    *acc = 0.0f;
  }
  for (int i = t; i < G; i += 64) btot[i] = 0;
}

// ---------------------------------------------------------------------------
// h = x @ conv_w   (32 threads per node, float4 loads)
// ---------------------------------------------------------------------------
__global__ void k_h(const float* __restrict__ x, const float* __restrict__ cw,
                    float* __restrict__ h, int n) {
  int gt = blockIdx.x * blockDim.x + threadIdx.x;
  int node = gt >> 5;
  int sub = gt & 31;
  if (node >= n) return;
  float4 xv = ((const float4*)x)[node * 32 + sub];
  float s0 = xv.x * cw[sub * 8 + 0] + xv.y * cw[sub * 8 + 2] +
             xv.z * cw[sub * 8 + 4] + xv.w * cw[sub * 8 + 6];
  float s1 = xv.x * cw[sub * 8 + 1] + xv.y * cw[sub * 8 + 3] +
             xv.z * cw[sub * 8 + 5] + xv.w * cw[sub * 8 + 7];
  for (int off = 16; off > 0; off >>= 1) {
    s0 += __shfl_down(s0, off, 32);
    s1 += __shfl_down(s1, off, 32);
  }
  if (sub == 0) { h[node * 2] = s0; h[node * 2 + 1] = s1; }
}

// ---------------------------------------------------------------------------
// edge bucketing: group = col >> 9  (512 destination nodes per group)
// ---------------------------------------------------------------------------
__global__ void k_hist(const void* ei, long long E, int G,
                       unsigned* table, unsigned* btot,
                       const unsigned* __restrict__ mode) {
  __shared__ unsigned hist[MAXG];
  unsigned m = *mode;
  int t = threadIdx.x;
  if (t < MAXG) hist[t] = 0;
  __syncthreads();
  long long perB = (E + HB - 1) / HB;
  long long base = (long long)blockIdx.x * perB;
  long long lim = base + perB; if (lim > E) lim = E;
  for (long long e = base + t; e < lim; e += HT) {
    int c = (int)edge_at(ei, E + e, m);
    atomicAdd(&hist[c >> 9], 1u);
  }
  __syncthreads();
  if (t < G) table[(size_t)t * HB + blockIdx.x] = hist[t];
}

// per-group totals (read one etab row per block)
__global__ void k_bsum(const unsigned* __restrict__ table, unsigned* btot) {
  int b = blockIdx.x, t = threadIdx.x;
  unsigned v = table[(size_t)b * HB + t];
  for (int off = 32; off > 0; off >>= 1) v += __shfl_down(v, off);
  __shared__ unsigned wsum[4];
  if ((t & 63) == 0) wsum[t >> 6] = v;
  __syncthreads();
  if (t == 0) btot[b] = wsum[0] + wsum[1] + wsum[2] + wsum[3];
}

// inline group prefix (from btot) + scan this group's 256 hist-block entries;
// also emits boff[]
__global__ void k_bapply(unsigned* table, const unsigned* __restrict__ btot,
                         unsigned* boff, int G, unsigned Etot) {
  __shared__ unsigned red[256];
  __shared__ unsigned s[256];
  int g = blockIdx.x, t = threadIdx.x;
  unsigned p = 0;
  for (int i = t; i < g; i += 256) p += btot[i];
  red[t] = p;
  __syncthreads();
  for (int off = 128; off > 0; off >>= 1) {
    if (t < off) red[t] += red[t + off];
    __syncthreads();
  }
  unsigned pre = red[0];
  unsigned v = table[(size_t)g * HB + t];
  s[t] = v;
  __syncthreads();
  for (int off = 1; off < 256; off <<= 1) {
    unsigned tmp = (t >= off) ? s[t - off] : 0u;
    __syncthreads();
    s[t] += tmp;
    __syncthreads();
  }
  table[(size_t)g * HB + t] = s[t] - v + pre;
  if (t == 0) { boff[g] = pre; if (g == 0) boff[G] = Etot; }
}

// scatter edges into coarse-group order
__global__ void k_scatter(const void* ei, const float* __restrict__ attr,
                          long long E, int G, const unsigned* __restrict__ table,
                          uint2* __restrict__ packed, const unsigned* __restrict__ mode) {
  __shared__ unsigned cur[MAXG];
  unsigned m = *mode;
  int t = threadIdx.x;
  if (t < G) cur[t] = table[(size_t)t * HB + blockIdx.x];
  __syncthreads();
  long long perB = (E + HB - 1) / HB;
  long long base = (long long)blockIdx.x * perB;
  long long lim = base + perB; if (lim > E) lim = E;
  for (long long e = base + t; e < lim; e += HT) {
    int r = (int)edge_at(ei, e, m);
    int c = (int)edge_at(ei, E + e, m);
    float a = attr[e];
    unsigned pos = atomicAdd(&cur[c >> 9], 1u);
    packed[pos] = make_uint2(((unsigned)r << 9) | ((unsigned)c & 511u), __float_as_uint(a));
  }
}

// ---------------------------------------------------------------------------
// S-split partial degree: pdeg[(g*S+s)*W + cl] = sum of attr (edges only)
// ---------------------------------------------------------------------------
__global__ void k_pdeg(const uint2* __restrict__ packed, const unsigned* __restrict__ boff,
                       float* __restrict__ pdeg) {
  __shared__ float sdeg[W];
  int blk = blockIdx.x, t = threadIdx.x;       // 256 threads
  int g = blk / S, s = blk - g * S;
  sdeg[t] = 0.f; sdeg[t + 256] = 0.f;
  __syncthreads();
  unsigned e0 = boff[g], e1 = boff[g + 1];
  unsigned len = e1 - e0;
  unsigned per = (len + S - 1) / S;
  unsigned lo = e0 + s * per;
  unsigned hi = lo + per; if (hi > e1) hi = e1;
  for (unsigned i = lo + t; i < hi; i += 256) {
    uint2 p = packed[i];
    atomicAdd(&sdeg[p.x & (W - 1u)], __uint_as_float(p.y));
  }
  __syncthreads();
  pdeg[(size_t)blk * W + t] = sdeg[t];
  pdeg[(size_t)blk * W + t + 256] = sdeg[t + 256];
}

// reduce partials: dinv = rsqrt(1 + sum_s pdeg); g[r] = dinv[r]*h[r]
__global__ void k_dinv(const float* __restrict__ pdeg, const float* __restrict__ h,
                       float* __restrict__ dinv, float* __restrict__ g, int n) {
  int i = blockIdx.x * blockDim.x + threadIdx.x;
  if (i >= n) return;
  int grp = i >> 9, li = i & (W - 1);
  float d = 1.0f;
#pragma unroll
  for (int s = 0; s < S; ++s) d += pdeg[((size_t)(grp * S + s)) * W + li];
  float di = rsqrtf(d);
  dinv[i] = di;
  g[2 * i]     = di * h[2 * i];
  g[2 * i + 1] = di * h[2 * i + 1];
}

// S-split partial messages: pacc[(g*S+s)*2W + 2*cl(+1)]
__global__ void k_pmsg(const uint2* __restrict__ packed, const unsigned* __restrict__ boff,
                       const float* __restrict__ gv, float* __restrict__ pacc) {
  __shared__ float sacc[2 * W];
  int blk = blockIdx.x, t = threadIdx.x;       // 256 threads
  int g = blk / S, s = blk - g * S;
#pragma unroll
  for (int i = 0; i < 4; ++i) sacc[t + 256 * i] = 0.f;
  __syncthreads();
  unsigned e0 = boff[g], e1 = boff[g + 1];
  unsigned len = e1 - e0;
  unsigned per = (len + S - 1) / S;
  unsigned lo = e0 + s * per;
  unsigned hi = lo + per; if (hi > e1) hi = e1;
  const float2* g2 = (const float2*)gv;
  for (unsigned i = lo + t; i < hi; i += 256) {
    uint2 p = packed[i];
    unsigned r = p.x >> 9;
    unsigned cl = p.x & (W - 1u);
    float a = __uint_as_float(p.y);
    float2 gr = g2[r];
    atomicAdd(&sacc[2 * cl],     a * gr.x);
    atomicAdd(&sacc[2 * cl + 1], a * gr.y);
  }
  __syncthreads();
#pragma unroll
  for (int i = 0; i < 4; ++i) pacc[(size_t)blk * (2 * W) + t + 256 * i] = sacc[t + 256 * i];
}

// reduce message partials + ReLU + score + sort keys
__global__ void k_gout(const float* __restrict__ pacc, const float* __restrict__ dinv,
                       const float* __restrict__ h, const float* __restrict__ cb,
                       const float* __restrict__ pw, float* __restrict__ out,
                       float* __restrict__ score, unsigned* __restrict__ keys,
                       unsigned* __restrict__ pay, int n) {
  int g = blockIdx.x, t = threadIdx.x;         // 512 threads
  const float2* p2 = (const float2*)pacc;
  float a0 = 0.f, a1 = 0.f;
#pragma unroll
  for (int s = 0; s < S; ++s) {
    float2 v = p2[(size_t)(g * S + s) * W + t];
    a0 += v.x; a1 += v.y;
  }
  int c = g * W + t;
  if (c < n) {
    float dc = dinv[c];
    float o0 = fmaxf(dc * a0 + dc * dc * h[2 * c]     + cb[0], 0.f);
    float o1 = fmaxf(dc * a1 + dc * dc * h[2 * c + 1] + cb[1], 0.f);
    out[2 * c] = o0; out[2 * c + 1] = o1;
    float pw0 = pw[0], pw1 = pw[1];
    float s = tanhf((o0 * pw0 + o1 * pw1) / sqrtf(pw0 * pw0 + pw1 * pw1));
    score[c] = s;
    unsigned u = __float_as_uint(s);
    unsigned asc = u ^ ((u >> 31) ? 0xFFFFFFFFu : 0x80000000u);
    keys[c] = ~asc;          // descending-order key, sort ascending
    pay[c] = (unsigned)c;
  }
}

// ---------------------------------------------------------------------------
// stable LSD radix sort, 4 x 8-bit passes; scatter builds next-pass histogram
// ---------------------------------------------------------------------------
__global__ void k_rhist0(const unsigned* __restrict__ keys, int n,
                         unsigned* tabA, unsigned* tabB) {
  __shared__ unsigned hist[256];
  int t = threadIdx.x;
  hist[t] = 0;
  __syncthreads();
  int base = blockIdx.x * 1024;
  for (int j = 0; j < 4; ++j) {
    int g = base + j * 256 + t;
    if (g < n) atomicAdd(&hist[keys[g] & 255u], 1u);
  }
  __syncthreads();
  tabA[t * BP + blockIdx.x] = hist[t];
  // zero tabB (next-pass hist accumulates atomically during scatter)
  for (int i = blockIdx.x * 256 + t; i < 256 * BP; i += gridDim.x * 256) tabB[i] = 0;
}

// block 0: exclusive scan of tab (digit-major rows); block 1: zero other table
__global__ void k_rscan(unsigned* tab, int B, unsigned* other) {
  int t = threadIdx.x;
  if (blockIdx.x == 1) {
    if (other) for (int i = t; i < 256 * BP; i += 256) other[i] = 0;
    return;
  }
  unsigned* row = tab + t * BP;
  uint4* r4 = (uint4*)row;
  int nv = B >> 2;
  unsigned s = 0;
#pragma unroll 8
  for (int i = 0; i < nv; ++i) { uint4 v = r4[i]; s += v.x + v.y + v.z + v.w; }
  for (int i = nv * 4; i < B; ++i) s += row[i];
  int lane = t & 63, w = t >> 6;
  unsigned inc = s;
  for (int off = 1; off < 64; off <<= 1) {
    unsigned nval = __shfl_up(inc, off);
    if (lane >= off) inc += nval;
  }
  __shared__ unsigned wtot[4];
  if (lane == 63) wtot[w] = inc;
  __syncthreads();
  unsigned wpre = 0;
  for (int i = 0; i < w; ++i) wpre += wtot[i];
  unsigned run = wpre + inc - s;
#pragma unroll 8
  for (int i = 0; i < nv; ++i) {
    uint4 v = r4[i]; uint4 o;
    o.x = run; run += v.x; o.y = run; run += v.y;
    o.z = run; run += v.z; o.w = run; run += v.w;
    r4[i] = o;
  }
  for (int i = nv * 4; i < B; ++i) { unsigned v = row[i]; row[i] = run; run += v; }
}

__global__ void k_rscatter(const unsigned* __restrict__ keysIn,
                           const unsigned* __restrict__ payIn, int n, int shift,
                           const unsigned* __restrict__ tabCur,
                           unsigned* keysOut, unsigned* payOut,
                           unsigned* tabNext) {
  __shared__ unsigned runCnt[256];
  __shared__ unsigned waveCnt[4 * 256];
  int t = threadIdx.x;
  int lane = t & 63, w = t >> 6;
  runCnt[t] = 0;
  int base = blockIdx.x * 1024;
  for (int j = 0; j < 4; ++j) {
    for (int q = t; q < 1024; q += 256) waveCnt[q] = 0;
    __syncthreads();
    int g = base + j * 256 + t;
    bool active = g < n;
    unsigned key = 0, pay = 0, d = 0;
    if (active) { key = keysIn[g]; pay = payIn[g]; d = (key >> shift) & 255u; }
    unsigned long long am = __ballot(active);
    unsigned long long mm = ~0ull;
#pragma unroll
    for (int b = 0; b < 8; ++b) {
      unsigned long long bb = __ballot((d >> b) & 1u);
      mm &= ((d >> b) & 1u) ? bb : ~bb;
    }
    mm &= am;
    int rankw = __popcll(mm & ((1ull << lane) - 1ull));
    if (active && rankw == 0) waveCnt[w * 256 + d] = (unsigned)__popcll(mm);
    __syncthreads();
    if (active) {
      unsigned off = runCnt[d] + (unsigned)rankw;
      for (int ww = 0; ww < w; ++ww) off += waveCnt[ww * 256 + d];
      unsigned gpos = tabCur[d * BP + blockIdx.x] + off;
      keysOut[gpos] = key;
      payOut[gpos] = pay;
      if (tabNext) {
        unsigned d2 = (key >> (shift + 8)) & 255u;
        atomicAdd(&tabNext[d2 * BP + (gpos >> 10)], 1u);
      }
    }
    __syncthreads();
    runCnt[t] += waveCnt[t] + waveCnt[256 + t] + waveCnt[512 + t] + waveCnt[768 + t];
    __syncthreads();
  }
}

// ---------------------------------------------------------------------------
// y-pre = sum_j score[perm[j]] * (out[perm[j]] . fc_w[2j:2j+2])
// ---------------------------------------------------------------------------
__global__ void k_final(const unsigned* __restrict__ perm, const float* __restrict__ out,
                        const float* __restrict__ score, const float* __restrict__ fcw,
                        float* acc, int n) {
  int stride = gridDim.x * blockDim.x;
  float s = 0.f;
  const float2* o2 = (const float2*)out;
  const float2* f2 = (const float2*)fcw;
  for (int j = blockIdx.x * blockDim.x + threadIdx.x; j < n; j += stride) {
    unsigned p = perm[j];
    float2 ov = o2[p];
    float2 fv = f2[j];
    s += score[p] * (ov.x * fv.x + ov.y * fv.y);
  }
  for (int off = 32; off > 0; off >>= 1) s += __shfl_down(s, off);
  if ((threadIdx.x & 63) == 0) atomic_fadd(acc, s);
}

__global__ void k_sigmoid(const float* acc, const float* __restrict__ fcb, float* y) {
  if (threadIdx.x == 0 && blockIdx.x == 0) {
    float z = *acc + fcb[0];
    y[0] = 1.f / (1.f + expf(-z));
  }
}

// ---------------------------------------------------------------------------
extern "C" void kernel_launch(void* const* d_in, const int* in_sizes, int n_in,
                              void* d_out, int out_size, void* d_ws, size_t ws_size,
                              hipStream_t stream) {
  const float* x     = (const float*)d_in[0];
  const void*  ei    = d_in[1];
  const float* attr  = (const float*)d_in[2];
  const float* convw = (const float*)d_in[3];
  const float* convb = (const float*)d_in[4];
  const float* poolw = (const float*)d_in[5];
  const float* fcw   = (const float*)d_in[6];
  const float* fcb   = (const float*)d_in[7];
  float* y = (float*)d_out;

  int N = in_sizes[0] / FIN;      // 100000
  long long E = in_sizes[2];      // 3200000
  int B = (N + 1023) / 1024;      // score radix chunks (98)
  int G = (N + W - 1) / W;        // 196 coarse groups

  // workspace carve (4-byte units; 8B alignment for uint2/float2 arrays)
  float* ws = (float*)d_ws;
  size_t off = 0;
  uint2* packed  = (uint2*)(ws + off); off += (size_t)2 * E;
  // pdeg aliases the low half of pacc (pdeg consumed by k_dinv before k_pmsg)
  float* pacc    = ws + off; off += (size_t)2 * G * S * W;
  float* pdeg    = pacc;
  float* h       = ws + off; off += (size_t)2 * N;
  float* dinv    = ws + off; off += (size_t)N;
  float* gv      = ws + off; off += (size_t)2 * N;
  float* outN    = ws + off; off += (size_t)2 * N;
  float* score   = ws + off; off += (size_t)N;
  unsigned* keysA = (unsigned*)(ws + off); off += (size_t)N;
  unsigned* payA  = (unsigned*)(ws + off); off += (size_t)N;
  unsigned* keysB = (unsigned*)(ws + off); off += (size_t)N;
  unsigned* payB  = (unsigned*)(ws + off); off += (size_t)N;
  unsigned* etab  = (unsigned*)(ws + off); off += (size_t)G * HB;
  unsigned* btot  = (unsigned*)(ws + off); off += (size_t)G;
  unsigned* boff  = (unsigned*)(ws + off); off += (size_t)G + 2;
  unsigned* tabA  = (unsigned*)(ws + off); off += (size_t)256 * BP;
  unsigned* tabB  = (unsigned*)(ws + off); off += (size_t)256 * BP;
  float* acc      = ws + off; off += 1;
  unsigned* mode  = (unsigned*)(ws + off); off += 1;

  int nb = (N + 255) / 256;

  k_detect<<<1, 64, 0, stream>>>((const unsigned*)ei, mode, acc, btot, G);
  k_h<<<(N * 32 + 255) / 256, 256, 0, stream>>>(x, convw, h, N);

  // ---- edge bucketing by destination coarse group ----
  k_hist<<<HB, HT, 0, stream>>>(ei, E, G, etab, btot, mode);
  k_bsum<<<G, 256, 0, stream>>>(etab, btot);
  k_bapply<<<G, 256, 0, stream>>>(etab, btot, boff, G, (unsigned)E);
  k_scatter<<<HB, HT, 0, stream>>>(ei, attr, E, G, etab, packed, mode);

  // ---- GCN conv via S-split grouped accumulation ----
  k_pdeg<<<G * S, 256, 0, stream>>>(packed, boff, pdeg);
  k_dinv<<<nb, 256, 0, stream>>>(pdeg, h, dinv, gv, N);
  k_pmsg<<<G * S, 256, 0, stream>>>(packed, boff, gv, pacc);
  k_gout<<<G, W, 0, stream>>>(pacc, dinv, h, convb, poolw, outN, score, keysA, payA, N);

  // ---- 4 stable radix passes: A->B->A->B->A (scatter builds next hist) ----
  k_rhist0<<<B, 256, 0, stream>>>(keysA, N, tabA, tabB);
  unsigned* ki = keysA; unsigned* pi = payA;
  unsigned* ko = keysB; unsigned* po = payB;
  unsigned* tc = tabA;  unsigned* tn = tabB;
  for (int p = 0; p < 4; ++p) {
    k_rscan<<<2, 256, 0, stream>>>(tc, B, (p == 0 || p == 3) ? (unsigned*)nullptr : tn);
    k_rscatter<<<B, 256, 0, stream>>>(ki, pi, N, 8 * p, tc,
                                      ko, po, (p < 3) ? tn : nullptr);
    unsigned* tk = ki; ki = ko; ko = tk;
    unsigned* tp = pi; pi = po; po = tp;
    unsigned* tt = tc; tc = tn; tn = tt;
  }
  // perm now in pi (== payA)

  k_final<<<196, 256, 0, stream>>>(pi, outN, score, fcw, acc, N);
  k_sigmoid<<<1, 64, 0, stream>>>(acc, fcb, y);
}

// Round 6
// 231.987 us; speedup vs baseline: 3.3121x; 3.3121x over previous
//
#include <hip/hip_runtime.h>
#include <math.h>

#define FIN 128
#define W 512          // nodes per coarse group
#define S 8            // sub-blocks per group for partial accumulation
#define MAXG 256       // LDS counter capacity (need G=196)
#define HB 256         // edge hist/scatter blocks
#define HT 1024        // edge hist/scatter threads per block
#define BP 100         // radix table padded stride (>= B=98, mult of 4)

// ---------------------------------------------------------------------------
// helpers
// ---------------------------------------------------------------------------
__device__ __forceinline__ long long edge_at(const void* p, long long i, unsigned mode) {
  return mode ? ((const long long*)p)[i] : (long long)((const int*)p)[i];
}

__device__ __forceinline__ void atomic_fadd(float* p, float v) {
  __hip_atomic_fetch_add(p, v, __ATOMIC_RELAXED, __HIP_MEMORY_SCOPE_AGENT);
}

// ---------------------------------------------------------------------------
// dtype detection + zero the final accumulator
// ---------------------------------------------------------------------------
__global__ void k_detect(const unsigned* ei, unsigned* mode, float* acc) {
  if (threadIdx.x == 0 && blockIdx.x == 0) {
    unsigned orv = 0;
    for (int i = 1; i < 1024; i += 2) orv |= ei[i];
    *mode = (orv == 0) ? 1u : 0u;
    *acc = 0.0f;
  }
}

// ---------------------------------------------------------------------------
// h = x @ conv_w   (32 threads per node, float4 loads)
// ---------------------------------------------------------------------------
__global__ void k_h(const float* __restrict__ x, const float* __restrict__ cw,
                    float* __restrict__ h, int n) {
  int gt = blockIdx.x * blockDim.x + threadIdx.x;
  int node = gt >> 5;
  int sub = gt & 31;
  if (node >= n) return;
  float4 xv = ((const float4*)x)[node * 32 + sub];
  float s0 = xv.x * cw[sub * 8 + 0] + xv.y * cw[sub * 8 + 2] +
             xv.z * cw[sub * 8 + 4] + xv.w * cw[sub * 8 + 6];
  float s1 = xv.x * cw[sub * 8 + 1] + xv.y * cw[sub * 8 + 3] +
             xv.z * cw[sub * 8 + 5] + xv.w * cw[sub * 8 + 7];
  for (int off = 16; off > 0; off >>= 1) {
    s0 += __shfl_down(s0, off, 32);
    s1 += __shfl_down(s1, off, 32);
  }
  if (sub == 0) { h[node * 2] = s0; h[node * 2 + 1] = s1; }
}

// ---------------------------------------------------------------------------
// edge bucketing: group = col >> 9  (512 destination nodes per group)
// ---------------------------------------------------------------------------
__global__ void k_hist(const void* ei, long long E, int G,
                       unsigned* table, const unsigned* __restrict__ mode) {
  __shared__ unsigned hist[MAXG];
  unsigned m = *mode;
  int t = threadIdx.x;
  if (t < MAXG) hist[t] = 0;
  __syncthreads();
  long long perB = (E + HB - 1) / HB;
  long long base = (long long)blockIdx.x * perB;
  long long lim = base + perB; if (lim > E) lim = E;
  for (long long e = base + t; e < lim; e += HT) {
    int c = (int)edge_at(ei, E + e, m);
    atomicAdd(&hist[c >> 9], 1u);
  }
  __syncthreads();
  if (t < G) table[(size_t)t * HB + blockIdx.x] = hist[t];
}

// per-group totals (read one etab row per block)
__global__ void k_bsum(const unsigned* __restrict__ table, unsigned* btot) {
  int b = blockIdx.x, t = threadIdx.x;
  unsigned v = table[(size_t)b * HB + t];
  for (int off = 32; off > 0; off >>= 1) v += __shfl_down(v, off);
  __shared__ unsigned wsum[4];
  if ((t & 63) == 0) wsum[t >> 6] = v;
  __syncthreads();
  if (t == 0) btot[b] = wsum[0] + wsum[1] + wsum[2] + wsum[3];
}

// inline group prefix (from btot) + scan this group's 256 hist-block entries;
// also emits boff[]
__global__ void k_bapply(unsigned* table, const unsigned* __restrict__ btot,
                         unsigned* boff, int G, unsigned Etot) {
  __shared__ unsigned red[256];
  __shared__ unsigned s[256];
  int g = blockIdx.x, t = threadIdx.x;
  unsigned p = 0;
  for (int i = t; i < g; i += 256) p += btot[i];
  red[t] = p;
  __syncthreads();
  for (int off = 128; off > 0; off >>= 1) {
    if (t < off) red[t] += red[t + off];
    __syncthreads();
  }
  unsigned pre = red[0];
  unsigned v = table[(size_t)g * HB + t];
  s[t] = v;
  __syncthreads();
  for (int off = 1; off < 256; off <<= 1) {
    unsigned tmp = (t >= off) ? s[t - off] : 0u;
    __syncthreads();
    s[t] += tmp;
    __syncthreads();
  }
  table[(size_t)g * HB + t] = s[t] - v + pre;
  if (t == 0) { boff[g] = pre; if (g == 0) boff[G] = Etot; }
}

// scatter edges into coarse-group order
__global__ void k_scatter(const void* ei, const float* __restrict__ attr,
                          long long E, int G, const unsigned* __restrict__ table,
                          uint2* __restrict__ packed, const unsigned* __restrict__ mode) {
  __shared__ unsigned cur[MAXG];
  unsigned m = *mode;
  int t = threadIdx.x;
  if (t < G) cur[t] = table[(size_t)t * HB + blockIdx.x];
  __syncthreads();
  long long perB = (E + HB - 1) / HB;
  long long base = (long long)blockIdx.x * perB;
  long long lim = base + perB; if (lim > E) lim = E;
  for (long long e = base + t; e < lim; e += HT) {
    int r = (int)edge_at(ei, e, m);
    int c = (int)edge_at(ei, E + e, m);
    float a = attr[e];
    unsigned pos = atomicAdd(&cur[c >> 9], 1u);
    packed[pos] = make_uint2(((unsigned)r << 9) | ((unsigned)c & 511u), __float_as_uint(a));
  }
}

// ---------------------------------------------------------------------------
// S-split partial degree: pdeg[(g*S+s)*W + cl] = sum of attr (edges only)
// ---------------------------------------------------------------------------
__global__ void k_pdeg(const uint2* __restrict__ packed, const unsigned* __restrict__ boff,
                       float* __restrict__ pdeg) {
  __shared__ float sdeg[W];
  int blk = blockIdx.x, t = threadIdx.x;       // 256 threads
  int g = blk / S, s = blk - g * S;
  sdeg[t] = 0.f; sdeg[t + 256] = 0.f;
  __syncthreads();
  unsigned e0 = boff[g], e1 = boff[g + 1];
  unsigned len = e1 - e0;
  unsigned per = (len + S - 1) / S;
  unsigned lo = e0 + s * per;
  unsigned hi = lo + per; if (hi > e1) hi = e1;
  for (unsigned i = lo + t; i < hi; i += 256) {
    uint2 p = packed[i];
    atomicAdd(&sdeg[p.x & (W - 1u)], __uint_as_float(p.y));
  }
  __syncthreads();
  pdeg[(size_t)blk * W + t] = sdeg[t];
  pdeg[(size_t)blk * W + t + 256] = sdeg[t + 256];
}

// reduce partials: dinv = rsqrt(1 + sum_s pdeg); g[r] = dinv[r]*h[r]
__global__ void k_dinv(const float* __restrict__ pdeg, const float* __restrict__ h,
                       float* __restrict__ dinv, float* __restrict__ g, int n) {
  int i = blockIdx.x * blockDim.x + threadIdx.x;
  if (i >= n) return;
  int grp = i >> 9, li = i & (W - 1);
  float d = 1.0f;
#pragma unroll
  for (int s = 0; s < S; ++s) d += pdeg[((size_t)(grp * S + s)) * W + li];
  float di = rsqrtf(d);
  dinv[i] = di;
  g[2 * i]     = di * h[2 * i];
  g[2 * i + 1] = di * h[2 * i + 1];
}

// S-split partial messages: pacc[(g*S+s)*2W + 2*cl(+1)]
__global__ void k_pmsg(const uint2* __restrict__ packed, const unsigned* __restrict__ boff,
                       const float* __restrict__ gv, float* __restrict__ pacc) {
  __shared__ float sacc[2 * W];
  int blk = blockIdx.x, t = threadIdx.x;       // 256 threads
  int g = blk / S, s = blk - g * S;
#pragma unroll
  for (int i = 0; i < 4; ++i) sacc[t + 256 * i] = 0.f;
  __syncthreads();
  unsigned e0 = boff[g], e1 = boff[g + 1];
  unsigned len = e1 - e0;
  unsigned per = (len + S - 1) / S;
  unsigned lo = e0 + s * per;
  unsigned hi = lo + per; if (hi > e1) hi = e1;
  const float2* g2 = (const float2*)gv;
  for (unsigned i = lo + t; i < hi; i += 256) {
    uint2 p = packed[i];
    unsigned r = p.x >> 9;
    unsigned cl = p.x & (W - 1u);
    float a = __uint_as_float(p.y);
    float2 gr = g2[r];
    atomicAdd(&sacc[2 * cl],     a * gr.x);
    atomicAdd(&sacc[2 * cl + 1], a * gr.y);
  }
  __syncthreads();
#pragma unroll
  for (int i = 0; i < 4; ++i) pacc[(size_t)blk * (2 * W) + t + 256 * i] = sacc[t + 256 * i];
}

// reduce message partials + ReLU + score + sort keys
__global__ void k_gout(const float* __restrict__ pacc, const float* __restrict__ dinv,
                       const float* __restrict__ h, const float* __restrict__ cb,
                       const float* __restrict__ pw, float* __restrict__ out,
                       float* __restrict__ score, unsigned* __restrict__ keys,
                       unsigned* __restrict__ pay, int n) {
  int g = blockIdx.x, t = threadIdx.x;         // 512 threads
  const float2* p2 = (const float2*)pacc;
  float a0 = 0.f, a1 = 0.f;
#pragma unroll
  for (int s = 0; s < S; ++s) {
    float2 v = p2[(size_t)(g * S + s) * W + t];
    a0 += v.x; a1 += v.y;
  }
  int c = g * W + t;
  if (c < n) {
    float dc = dinv[c];
    float o0 = fmaxf(dc * a0 + dc * dc * h[2 * c]     + cb[0], 0.f);
    float o1 = fmaxf(dc * a1 + dc * dc * h[2 * c + 1] + cb[1], 0.f);
    out[2 * c] = o0; out[2 * c + 1] = o1;
    float pw0 = pw[0], pw1 = pw[1];
    float s = tanhf((o0 * pw0 + o1 * pw1) / sqrtf(pw0 * pw0 + pw1 * pw1));
    score[c] = s;
    unsigned u = __float_as_uint(s);
    unsigned asc = u ^ ((u >> 31) ? 0xFFFFFFFFu : 0x80000000u);
    keys[c] = ~asc;          // descending-order key, sort ascending
    pay[c] = (unsigned)c;
  }
}

// ---------------------------------------------------------------------------
// stable LSD radix sort, 4 x 8-bit passes (round-4 proven structure:
// per-pass LDS-hist kernel; NO global-atomic fused histogram — that ran at
// ~0.5 G atomics/s under 1.6% occupancy and cost 189 us/pass)
// ---------------------------------------------------------------------------
__global__ void k_radix_hist(const unsigned* __restrict__ keys, int n, int shift,
                             unsigned* table) {
  __shared__ unsigned hist[256];
  int t = threadIdx.x;
  hist[t] = 0;
  __syncthreads();
  int base = blockIdx.x * 1024;
  for (int j = 0; j < 4; ++j) {
    int g = base + j * 256 + t;
    if (g < n) {
      unsigned d = (keys[g] >> shift) & 255u;
      atomicAdd(&hist[d], 1u);
    }
  }
  __syncthreads();
  table[t * BP + blockIdx.x] = hist[t];   // digit-major, padded stride
}

// parallel scan over the whole digit-major table (256 rows x B entries)
__global__ void k_radix_scan(unsigned* table, int B) {
  int t = threadIdx.x;                    // 256 threads, one digit row each
  unsigned* row = table + t * BP;
  uint4* r4 = (uint4*)row;
  int nv = B >> 2;
  unsigned s = 0;
#pragma unroll 8
  for (int i = 0; i < nv; ++i) { uint4 v = r4[i]; s += v.x + v.y + v.z + v.w; }
  for (int i = nv * 4; i < B; ++i) s += row[i];
  int lane = t & 63, w = t >> 6;
  unsigned inc = s;
  for (int off = 1; off < 64; off <<= 1) {
    unsigned nval = __shfl_up(inc, off);
    if (lane >= off) inc += nval;
  }
  __shared__ unsigned wtot[4];
  if (lane == 63) wtot[w] = inc;
  __syncthreads();
  unsigned wpre = 0;
  for (int i = 0; i < w; ++i) wpre += wtot[i];
  unsigned run = wpre + inc - s;          // exclusive prefix of this row
#pragma unroll 8
  for (int i = 0; i < nv; ++i) {
    uint4 v = r4[i]; uint4 o;
    o.x = run; run += v.x; o.y = run; run += v.y;
    o.z = run; run += v.z; o.w = run; run += v.w;
    r4[i] = o;
  }
  for (int i = nv * 4; i < B; ++i) { unsigned v = row[i]; row[i] = run; run += v; }
}

__global__ void k_radix_scatter(const unsigned* __restrict__ keysIn,
                                const unsigned* __restrict__ payIn, int n, int shift,
                                const unsigned* __restrict__ table,
                                unsigned* keysOut, unsigned* payOut) {
  __shared__ unsigned runCnt[256];
  __shared__ unsigned waveCnt[4 * 256];
  int t = threadIdx.x;
  int lane = t & 63, w = t >> 6;
  runCnt[t] = 0;
  int base = blockIdx.x * 1024;
  for (int j = 0; j < 4; ++j) {
    for (int q = t; q < 1024; q += 256) waveCnt[q] = 0;
    __syncthreads();
    int g = base + j * 256 + t;
    bool active = g < n;
    unsigned key = 0, pay = 0, d = 0;
    if (active) { key = keysIn[g]; pay = payIn[g]; d = (key >> shift) & 255u; }
    unsigned long long am = __ballot(active);
    unsigned long long mm = ~0ull;
#pragma unroll
    for (int b = 0; b < 8; ++b) {
      unsigned long long bb = __ballot((d >> b) & 1u);
      mm &= ((d >> b) & 1u) ? bb : ~bb;
    }
    mm &= am;
    int rankw = __popcll(mm & ((1ull << lane) - 1ull));
    if (active && rankw == 0) waveCnt[w * 256 + d] = (unsigned)__popcll(mm);
    __syncthreads();
    if (active) {
      unsigned off = runCnt[d] + (unsigned)rankw;
      for (int ww = 0; ww < w; ++ww) off += waveCnt[ww * 256 + d];
      unsigned gpos = table[d * BP + blockIdx.x] + off;
      keysOut[gpos] = key;
      payOut[gpos] = pay;
    }
    __syncthreads();
    runCnt[t] += waveCnt[t] + waveCnt[256 + t] + waveCnt[512 + t] + waveCnt[768 + t];
    __syncthreads();
  }
}

// ---------------------------------------------------------------------------
// y-pre = sum_j score[perm[j]] * (out[perm[j]] . fc_w[2j:2j+2])
// ---------------------------------------------------------------------------
__global__ void k_final(const unsigned* __restrict__ perm, const float* __restrict__ out,
                        const float* __restrict__ score, const float* __restrict__ fcw,
                        float* acc, int n) {
  int stride = gridDim.x * blockDim.x;
  float s = 0.f;
  const float2* o2 = (const float2*)out;
  const float2* f2 = (const float2*)fcw;
  for (int j = blockIdx.x * blockDim.x + threadIdx.x; j < n; j += stride) {
    unsigned p = perm[j];
    float2 ov = o2[p];
    float2 fv = f2[j];
    s += score[p] * (ov.x * fv.x + ov.y * fv.y);
  }
  for (int off = 32; off > 0; off >>= 1) s += __shfl_down(s, off);
  if ((threadIdx.x & 63) == 0) atomic_fadd(acc, s);
}

__global__ void k_sigmoid(const float* acc, const float* __restrict__ fcb, float* y) {
  if (threadIdx.x == 0 && blockIdx.x == 0) {
    float z = *acc + fcb[0];
    y[0] = 1.f / (1.f + expf(-z));
  }
}

// ---------------------------------------------------------------------------
extern "C" void kernel_launch(void* const* d_in, const int* in_sizes, int n_in,
                              void* d_out, int out_size, void* d_ws, size_t ws_size,
                              hipStream_t stream) {
  const float* x     = (const float*)d_in[0];
  const void*  ei    = d_in[1];
  const float* attr  = (const float*)d_in[2];
  const float* convw = (const float*)d_in[3];
  const float* convb = (const float*)d_in[4];
  const float* poolw = (const float*)d_in[5];
  const float* fcw   = (const float*)d_in[6];
  const float* fcb   = (const float*)d_in[7];
  float* y = (float*)d_out;

  int N = in_sizes[0] / FIN;      // 100000
  long long E = in_sizes[2];      // 3200000
  int B = (N + 1023) / 1024;      // score radix chunks (98)
  int G = (N + W - 1) / W;        // 196 coarse groups

  // workspace carve (4-byte units; 8B alignment for uint2/float2 arrays)
  float* ws = (float*)d_ws;
  size_t off = 0;
  uint2* packed  = (uint2*)(ws + off); off += (size_t)2 * E;
  // pdeg aliases the low half of pacc (pdeg consumed by k_dinv before k_pmsg)
  float* pacc    = ws + off; off += (size_t)2 * G * S * W;
  float* pdeg    = pacc;
  float* h       = ws + off; off += (size_t)2 * N;
  float* dinv    = ws + off; off += (size_t)N;
  float* gv      = ws + off; off += (size_t)2 * N;
  float* outN    = ws + off; off += (size_t)2 * N;
  float* score   = ws + off; off += (size_t)N;
  unsigned* keysA = (unsigned*)(ws + off); off += (size_t)N;
  unsigned* payA  = (unsigned*)(ws + off); off += (size_t)N;
  unsigned* keysB = (unsigned*)(ws + off); off += (size_t)N;
  unsigned* payB  = (unsigned*)(ws + off); off += (size_t)N;
  unsigned* etab  = (unsigned*)(ws + off); off += (size_t)G * HB;
  unsigned* btot  = (unsigned*)(ws + off); off += (size_t)G;
  unsigned* boff  = (unsigned*)(ws + off); off += (size_t)G + 2;
  unsigned* stab  = (unsigned*)(ws + off); off += (size_t)256 * BP;
  float* acc      = ws + off; off += 1;
  unsigned* mode  = (unsigned*)(ws + off); off += 1;

  int nb = (N + 255) / 256;

  k_detect<<<1, 64, 0, stream>>>((const unsigned*)ei, mode, acc);
  k_h<<<(N * 32 + 255) / 256, 256, 0, stream>>>(x, convw, h, N);

  // ---- edge bucketing by destination coarse group ----
  k_hist<<<HB, HT, 0, stream>>>(ei, E, G, etab, mode);
  k_bsum<<<G, 256, 0, stream>>>(etab, btot);
  k_bapply<<<G, 256, 0, stream>>>(etab, btot, boff, G, (unsigned)E);
  k_scatter<<<HB, HT, 0, stream>>>(ei, attr, E, G, etab, packed, mode);

  // ---- GCN conv via S-split grouped accumulation ----
  k_pdeg<<<G * S, 256, 0, stream>>>(packed, boff, pdeg);
  k_dinv<<<nb, 256, 0, stream>>>(pdeg, h, dinv, gv, N);
  k_pmsg<<<G * S, 256, 0, stream>>>(packed, boff, gv, pacc);
  k_gout<<<G, W, 0, stream>>>(pacc, dinv, h, convb, poolw, outN, score, keysA, payA, N);

  // ---- 4 stable radix passes: A->B->A->B->A ----
  unsigned* ki = keysA; unsigned* pi = payA;
  unsigned* ko = keysB; unsigned* po = payB;
  for (int p = 0; p < 4; ++p) {
    int shift = 8 * p;
    k_radix_hist<<<B, 256, 0, stream>>>(ki, N, shift, stab);
    k_radix_scan<<<1, 256, 0, stream>>>(stab, B);
    k_radix_scatter<<<B, 256, 0, stream>>>(ki, pi, N, shift, stab, ko, po);
    unsigned* tk = ki; ki = ko; ko = tk;
    unsigned* tp = pi; pi = po; po = tp;
  }
  // perm now in pi (== payA)

  k_final<<<196, 256, 0, stream>>>(pi, outN, score, fcw, acc, N);
  k_sigmoid<<<1, 64, 0, stream>>>(acc, fcb, y);
}